// Round 4
// baseline (1224.998 us; speedup 1.0000x reference)
//
#include <hip/hip_runtime.h>
#include <hip/hip_bf16.h>
#include <math.h>

#define B_   128
#define S_   1024
#define EMB_ 128
#define HID_ 128
#define NL_  9
#define NPOS (B_ * S_)          // 131072
#define NBLK_HEAD (NPOS / 128)  // 1024

typedef __bf16 bf16x4 __attribute__((ext_vector_type(4)));
typedef __bf16 bf16x8 __attribute__((ext_vector_type(8)));
typedef float  f32x4  __attribute__((ext_vector_type(4)));

#define LDSK 136   // 128 + 8 bf16 pad: rows stay 16B-aligned (272B stride)

// LDS-only barrier: inter-wave contract is LDS writes; skip the vmcnt(0)
// drain __syncthreads() would emit (global stores are fire-and-forget).
#define LDS_BARRIER() __asm__ volatile("s_waitcnt lgkmcnt(0)\n\ts_barrier" ::: "memory")

__device__ __forceinline__ float fast_tanh(float x) {
    // tanh(x) = 1 - 2/(2^(x*2*log2(e)) + 1); exact saturation at +-inf
    float e = __builtin_amdgcn_exp2f(x * 2.885390081777927f);  // v_exp_f32
    return 1.0f - 2.0f * __builtin_amdgcn_rcpf(e + 1.0f);
}

// ---------------------------------------------------------------------------
// K1 (rewritten): xw = gather(emb, ids) @ Wx + b_h as bf16 MFMA GEMM.
// 1024 blocks x 256 thr; block = 128 positions x 128 cols.
// A-tile (gathered emb rows, bf16) staged in LDS; Wx frags in registers.
// ---------------------------------------------------------------------------
__global__ __launch_bounds__(256, 2) void xw_mfma_kernel(
    const int* __restrict__ ids,
    const float* __restrict__ emb,
    const float* __restrict__ W_h,
    const float* __restrict__ b_h,
    float* __restrict__ xw)
{
    const int tid  = threadIdx.x;
    const int wave = tid >> 6;
    const int lane = tid & 63;
    const int l    = lane & 15;
    const int q    = lane >> 4;
    const int base = blockIdx.x * 128;

    __shared__ int ids_s[128];
    __shared__ __align__(16) __bf16 A[128][LDSK];

    if (tid < 128) ids_s[tid] = ids[base + tid];

    // --- B fragments (Wx): n = wave*32 + nl*16 + l, k = kt*32 + q*8 + j
    bf16x8 wfrag[4][2];
#pragma unroll
    for (int kt = 0; kt < 4; ++kt)
#pragma unroll
        for (int nl = 0; nl < 2; ++nl) {
            const int n = wave * 32 + nl * 16 + l;
            const int kb = kt * 32 + q * 8;
            bf16x8 f;
#pragma unroll
            for (int j = 0; j < 8; ++j)
                f[j] = (__bf16)W_h[(size_t)(kb + j) * HID_ + n];
            wfrag[kt][nl] = f;
        }
    float bhv[2];
#pragma unroll
    for (int nl = 0; nl < 2; ++nl)
        bhv[nl] = b_h[wave * 32 + nl * 16 + l];

    __syncthreads();   // ids_s ready

    // --- gather 128 emb rows -> bf16 LDS tile (8 rows per iteration)
    const int lr = tid >> 5;          // 0..7
    const int c4 = (tid & 31) * 4;    // 0..124
#pragma unroll 4
    for (int r0 = 0; r0 < 128; r0 += 8) {
        const int row = r0 + lr;
        const float4 v = *(const float4*)&emb[(size_t)ids_s[row] * EMB_ + c4];
        bf16x4 b = {(__bf16)v.x, (__bf16)v.y, (__bf16)v.z, (__bf16)v.w};
        *(bf16x4*)&A[row][c4] = b;
    }
    __syncthreads();   // A ready

    // --- 8 M-tiles per wave; each wave owns 32 N-cols
#pragma unroll 1
    for (int mt = 0; mt < 8; ++mt) {
        bf16x8 afrag[4];
#pragma unroll
        for (int kt = 0; kt < 4; ++kt)
            afrag[kt] = *(const bf16x8*)&A[mt * 16 + l][kt * 32 + q * 8];

        f32x4 acc0 = {0.f, 0.f, 0.f, 0.f};
        f32x4 acc1 = {0.f, 0.f, 0.f, 0.f};
#pragma unroll
        for (int kt = 0; kt < 4; ++kt) {
            acc0 = __builtin_amdgcn_mfma_f32_16x16x32_bf16(
                       afrag[kt], wfrag[kt][0], acc0, 0, 0, 0);
            acc1 = __builtin_amdgcn_mfma_f32_16x16x32_bf16(
                       afrag[kt], wfrag[kt][1], acc1, 0, 0, 0);
        }
        // C layout: col n = <wave cols>+l, row m = mt*16 + q*4 + r
#pragma unroll
        for (int nl = 0; nl < 2; ++nl) {
            const int n = wave * 32 + nl * 16 + l;
#pragma unroll
            for (int r = 0; r < 4; ++r) {
                const int row = base + mt * 16 + q * 4 + r;
                const float vv = (nl ? acc1[r] : acc0[r]) + bhv[nl];
                xw[(size_t)row * HID_ + n] = vv;
            }
        }
    }
}

// ---------------------------------------------------------------------------
// K2 (restructured): MFMA recurrence, 2 independent batch-groups per block.
// 4 blocks x 256 thr; block owns groups 2b, 2b+1 (16 batches each).
// LDS-only barriers (no vmcnt drain); xw prefetched 2 steps ahead at loop
// top; hs stored fp32 in-place (fire-and-forget).
// ---------------------------------------------------------------------------
__global__ __launch_bounds__(256, 1) void rnn_mfma_kernel(
    const float* __restrict__ W_h,
    float* __restrict__ xw)
{
    const int wave = threadIdx.x >> 6;
    const int lane = threadIdx.x & 63;
    const int l    = lane & 15;
    const int q    = lane >> 4;

    // --- B fragments (Wh), shared by both groups
    bf16x8 wfrag[4][2];
#pragma unroll
    for (int kt = 0; kt < 4; ++kt)
#pragma unroll
        for (int nl = 0; nl < 2; ++nl) {
            const int n = wave * 32 + nl * 16 + l;
            const int kb = kt * 32 + q * 8;
            bf16x8 f;
#pragma unroll
            for (int j = 0; j < 8; ++j)
                f[j] = (__bf16)W_h[(size_t)(EMB_ + kb + j) * HID_ + n];
            wfrag[kt][nl] = f;
        }

    // --- h double buffers, per group
    __shared__ __align__(16) __bf16 hl[2][2][16 * LDSK];   // [group][buf]
    for (int i = threadIdx.x; i < 2 * 2 * 16 * LDSK; i += 256)
        (&hl[0][0][0])[i] = (__bf16)0.f;

    // --- xw element offsets, C-fragment order: (G, nl, r)
    int off[2][2][4];
#pragma unroll
    for (int G = 0; G < 2; ++G)
#pragma unroll
        for (int nl = 0; nl < 2; ++nl)
#pragma unroll
            for (int r = 0; r < 4; ++r)
                off[G][nl][r] =
                    ((blockIdx.x * 2 + G) * 16 + q * 4 + r) * (S_ * HID_)
                    + wave * 32 + nl * 16 + l;

    // prefetch x_0 (buf 0) and x_1 (buf 1)
    float xb[2][2][2][4];   // [G][buf][nl][r]
#pragma unroll
    for (int G = 0; G < 2; ++G)
#pragma unroll
        for (int nl = 0; nl < 2; ++nl)
#pragma unroll
            for (int r = 0; r < 4; ++r) {
                xb[G][0][nl][r] = xw[off[G][nl][r]];
                xb[G][1][nl][r] = xw[off[G][nl][r] + HID_];
            }

    __syncthreads();   // h init visible (full sync once is fine)

#pragma unroll 1
    for (int t = 0; t < S_; t += 2) {
#pragma unroll
        for (int u = 0; u < 2; ++u) {          // sub-step t+u, buf = u
            // 1) prefetch x_{t+u+2} first (fire loads early)
            float xf[2][2][4];
#pragma unroll
            for (int G = 0; G < 2; ++G)
#pragma unroll
                for (int nl = 0; nl < 2; ++nl)
#pragma unroll
                    for (int r = 0; r < 4; ++r)
                        xf[G][nl][r] = xw[off[G][nl][r] + (t + u + 2) * HID_];

            // 2) A fragments for both groups
            bf16x8 af[2][4];
#pragma unroll
            for (int G = 0; G < 2; ++G)
#pragma unroll
                for (int kt = 0; kt < 4; ++kt)
                    af[G][kt] = *(const bf16x8*)
                        &hl[G][u][l * LDSK + kt * 32 + q * 8];

            // 3) MFMAs (16 total, two independent chains)
            f32x4 acc[2][2];
#pragma unroll
            for (int G = 0; G < 2; ++G)
#pragma unroll
                for (int nl = 0; nl < 2; ++nl)
                    acc[G][nl] = (f32x4){0.f, 0.f, 0.f, 0.f};
#pragma unroll
            for (int kt = 0; kt < 4; ++kt)
#pragma unroll
                for (int G = 0; G < 2; ++G) {
                    acc[G][0] = __builtin_amdgcn_mfma_f32_16x16x32_bf16(
                                    af[G][kt], wfrag[kt][0], acc[G][0], 0, 0, 0);
                    acc[G][1] = __builtin_amdgcn_mfma_f32_16x16x32_bf16(
                                    af[G][kt], wfrag[kt][1], acc[G][1], 0, 0, 0);
                }

            // 4) epilogue: +xw, tanh, hs store (fire-and-forget), h stage
#pragma unroll
            for (int G = 0; G < 2; ++G) {
                __bf16* hdst = &hl[G][u ^ 1][0];
#pragma unroll
                for (int nl = 0; nl < 2; ++nl)
#pragma unroll
                    for (int r = 0; r < 4; ++r) {
                        const float pre = acc[G][nl][r] + xb[G][u][nl][r];
                        const float hf  = fast_tanh(pre);
                        xw[off[G][nl][r] + (t + u) * HID_] = hf;
                        xb[G][u][nl][r] = xf[G][nl][r];
                        hdst[(q * 4 + r) * LDSK + wave * 32 + nl * 16 + l] =
                            (__bf16)hf;
                    }
            }
            LDS_BARRIER();   // LDS-only: no vmcnt drain
        }
    }
    // NOTE: t+2 prefetch reads up to 2 rows past xw for the last batch; that
    // lands in the partial[] scratch region of d_ws (read-only here, values
    // unused, partial is written only later by head_kernel).
}

// ---------------------------------------------------------------------------
// K3: logits + log-softmax + per-block NLL partials   (unchanged)
// ---------------------------------------------------------------------------
__global__ __launch_bounds__(128, 2) void head_kernel(
    const float* __restrict__ hs,
    const float* __restrict__ W_out,
    const float* __restrict__ b_out,
    const int* __restrict__ labels,
    float* __restrict__ logits,
    float* __restrict__ partial)
{
    __shared__ float tile[128][129];
    __shared__ float wT[NL_][HID_];
    __shared__ float red[2];

    const int j = threadIdx.x;
    const int tpos = blockIdx.x * 128;

#pragma unroll
    for (int l = 0; l < NL_; ++l) wT[l][j] = W_out[j * NL_ + l];

    for (int p = 0; p < 128; ++p)
        tile[p][j] = hs[(size_t)(tpos + p) * HID_ + j];
    __syncthreads();

    float acc[NL_];
#pragma unroll
    for (int l = 0; l < NL_; ++l) acc[l] = b_out[l];

#pragma unroll 4
    for (int e = 0; e < HID_; ++e) {
        const float hv = tile[j][e];
#pragma unroll
        for (int l = 0; l < NL_; ++l) acc[l] += hv * wT[l][e];
    }

    float m = acc[0];
#pragma unroll
    for (int l = 1; l < NL_; ++l) m = fmaxf(m, acc[l]);
    float s = 0.f;
#pragma unroll
    for (int l = 0; l < NL_; ++l) s += __expf(acc[l] - m);
    const float logZ = m + __logf(s);

    const int lab = labels[tpos + j];
    float accl = 0.f;
#pragma unroll
    for (int l = 0; l < NL_; ++l) accl = (l == lab) ? acc[l] : accl;
    float v = logZ - accl;

#pragma unroll
    for (int off = 32; off > 0; off >>= 1) v += __shfl_down(v, off, 64);

    __syncthreads();
    if ((j & 63) == 0) red[j >> 6] = v;

    float* lt = &tile[0][0];
#pragma unroll
    for (int l = 0; l < NL_; ++l) lt[j * NL_ + l] = acc[l];
    __syncthreads();

    if (j == 0) partial[blockIdx.x] = red[0] + red[1];
    for (int i = j; i < 128 * NL_; i += 128)
        logits[(size_t)tpos * NL_ + i] = lt[i];
}

// ---------------------------------------------------------------------------
// K4: reduce partials -> loss scalar   (unchanged)
// ---------------------------------------------------------------------------
__global__ __launch_bounds__(256) void loss_kernel(
    const float* __restrict__ partial,
    float* __restrict__ out)
{
    __shared__ float red[4];
    const int j = threadIdx.x;
    float s = 0.f;
    for (int i = j; i < NBLK_HEAD; i += 256) s += partial[i];
#pragma unroll
    for (int off = 32; off > 0; off >>= 1) s += __shfl_down(s, off, 64);
    if ((j & 63) == 0) red[j >> 6] = s;
    __syncthreads();
    if (j == 0)
        out[(size_t)NPOS * NL_] =
            (red[0] + red[1] + red[2] + red[3]) * (1.0f / (float)NPOS);
}

// ---------------------------------------------------------------------------
extern "C" void kernel_launch(void* const* d_in, const int* in_sizes, int n_in,
                              void* d_out, int out_size, void* d_ws, size_t ws_size,
                              hipStream_t stream) {
    const int*   ids    = (const int*)d_in[0];
    const int*   labels = (const int*)d_in[3];
    const float* emb    = (const float*)d_in[4];
    const float* W_h    = (const float*)d_in[5];
    const float* b_h    = (const float*)d_in[6];
    const float* W_out  = (const float*)d_in[7];
    const float* b_out  = (const float*)d_in[8];
    float* out = (float*)d_out;

    float* xw      = (float*)d_ws;              // NPOS*HID floats (64 MB)
    float* partial = xw + (size_t)NPOS * HID_;  // NBLK_HEAD floats

    xw_mfma_kernel<<<NBLK_HEAD, 256, 0, stream>>>(ids, emb, W_h, b_h, xw);
    rnn_mfma_kernel<<<B_ / 32,  256, 0, stream>>>(W_h, xw);
    head_kernel   <<<NBLK_HEAD, 128, 0, stream>>>(xw, W_out, b_out, labels, out, partial);
    loss_kernel   <<<1,         256, 0, stream>>>(partial, out);
}

// Round 5
// 644.782 us; speedup vs baseline: 1.8999x; 1.8999x over previous
//
#include <hip/hip_runtime.h>
#include <hip/hip_bf16.h>
#include <math.h>

#define B_   128
#define S_   1024
#define EMB_ 128
#define HID_ 128
#define NL_  9
#define NPOS (B_ * S_)          // 131072
#define NBLK_HEAD (NPOS / 128)  // 1024

typedef __bf16 bf16x4 __attribute__((ext_vector_type(4)));
typedef __bf16 bf16x8 __attribute__((ext_vector_type(8)));
typedef float  f32x4  __attribute__((ext_vector_type(4)));

#define LDSK 136   // 128 + 8 bf16 pad: rows stay 16B-aligned (272B stride)

// LDS-only barrier: inter-wave contract is LDS writes; skip the vmcnt(0)
// drain __syncthreads() would emit (global loads/stores stay in flight).
#define LDS_BARRIER() __asm__ volatile("s_waitcnt lgkmcnt(0)\n\ts_barrier" ::: "memory")

__device__ __forceinline__ float fast_tanh(float x) {
    // tanh(x) = 1 - 2/(2^(x*2*log2(e)) + 1); exact saturation at +-inf
    float e = __builtin_amdgcn_exp2f(x * 2.885390081777927f);  // v_exp_f32
    return 1.0f - 2.0f * __builtin_amdgcn_rcpf(e + 1.0f);
}

// ---------------------------------------------------------------------------
// K1: xw = gather(emb, ids) @ Wx + b_h as bf16 MFMA GEMM.   (unchanged)
// ---------------------------------------------------------------------------
__global__ __launch_bounds__(256, 2) void xw_mfma_kernel(
    const int* __restrict__ ids,
    const float* __restrict__ emb,
    const float* __restrict__ W_h,
    const float* __restrict__ b_h,
    float* __restrict__ xw)
{
    const int tid  = threadIdx.x;
    const int wave = tid >> 6;
    const int lane = tid & 63;
    const int l    = lane & 15;
    const int q    = lane >> 4;
    const int base = blockIdx.x * 128;

    __shared__ int ids_s[128];
    __shared__ __align__(16) __bf16 A[128][LDSK];

    if (tid < 128) ids_s[tid] = ids[base + tid];

    bf16x8 wfrag[4][2];
#pragma unroll
    for (int kt = 0; kt < 4; ++kt)
#pragma unroll
        for (int nl = 0; nl < 2; ++nl) {
            const int n = wave * 32 + nl * 16 + l;
            const int kb = kt * 32 + q * 8;
            bf16x8 f;
#pragma unroll
            for (int j = 0; j < 8; ++j)
                f[j] = (__bf16)W_h[(size_t)(kb + j) * HID_ + n];
            wfrag[kt][nl] = f;
        }
    float bhv[2];
#pragma unroll
    for (int nl = 0; nl < 2; ++nl)
        bhv[nl] = b_h[wave * 32 + nl * 16 + l];

    __syncthreads();   // ids_s ready

    const int lr = tid >> 5;          // 0..7
    const int c4 = (tid & 31) * 4;    // 0..124
#pragma unroll 4
    for (int r0 = 0; r0 < 128; r0 += 8) {
        const int row = r0 + lr;
        const float4 v = *(const float4*)&emb[(size_t)ids_s[row] * EMB_ + c4];
        bf16x4 b = {(__bf16)v.x, (__bf16)v.y, (__bf16)v.z, (__bf16)v.w};
        *(bf16x4*)&A[row][c4] = b;
    }
    __syncthreads();   // A ready

#pragma unroll 1
    for (int mt = 0; mt < 8; ++mt) {
        bf16x8 afrag[4];
#pragma unroll
        for (int kt = 0; kt < 4; ++kt)
            afrag[kt] = *(const bf16x8*)&A[mt * 16 + l][kt * 32 + q * 8];

        f32x4 acc0 = {0.f, 0.f, 0.f, 0.f};
        f32x4 acc1 = {0.f, 0.f, 0.f, 0.f};
#pragma unroll
        for (int kt = 0; kt < 4; ++kt) {
            acc0 = __builtin_amdgcn_mfma_f32_16x16x32_bf16(
                       afrag[kt], wfrag[kt][0], acc0, 0, 0, 0);
            acc1 = __builtin_amdgcn_mfma_f32_16x16x32_bf16(
                       afrag[kt], wfrag[kt][1], acc1, 0, 0, 0);
        }
#pragma unroll
        for (int nl = 0; nl < 2; ++nl) {
            const int n = wave * 32 + nl * 16 + l;
#pragma unroll
            for (int r = 0; r < 4; ++r) {
                const int row = base + mt * 16 + q * 4 + r;
                const float vv = (nl ? acc1[r] : acc0[r]) + bhv[nl];
                xw[(size_t)row * HID_ + n] = vv;
            }
        }
    }
}

// ---------------------------------------------------------------------------
// K2 (R5): MFMA recurrence, 8 blocks x 4 waves, 16 batches/block.
// Software pipeline: unroll x4, 4 rotating x-register slots, prefetch
// distance 4 (load issued after its slot is consumed, waited 4 barriers
// later). LDS-only barriers; hs stores fire-and-forget.
// ---------------------------------------------------------------------------
__global__ __launch_bounds__(256, 1) void rnn_mfma_kernel(
    const float* __restrict__ W_h,
    float* __restrict__ xw)
{
    const int wave = threadIdx.x >> 6;
    const int lane = threadIdx.x & 63;
    const int l    = lane & 15;
    const int q    = lane >> 4;
    const int b0   = blockIdx.x * 16;

    // B fragments (Wh): n = wave*32 + nl*16 + l, k = kt*32 + q*8 + j
    bf16x8 wfrag[4][2];
#pragma unroll
    for (int kt = 0; kt < 4; ++kt)
#pragma unroll
        for (int nl = 0; nl < 2; ++nl) {
            const int n = wave * 32 + nl * 16 + l;
            const int kb = kt * 32 + q * 8;
            bf16x8 f;
#pragma unroll
            for (int j = 0; j < 8; ++j)
                f[j] = (__bf16)W_h[(size_t)(EMB_ + kb + j) * HID_ + n];
            wfrag[kt][nl] = f;
        }

    // h double buffer
    __shared__ __align__(16) __bf16 hl[2][16 * LDSK];
    for (int i = threadIdx.x; i < 2 * 16 * LDSK; i += 256)
        (&hl[0][0])[i] = (__bf16)0.f;

    // xw element offsets, C-fragment order
    int off[2][4];
#pragma unroll
    for (int nl = 0; nl < 2; ++nl)
#pragma unroll
        for (int r = 0; r < 4; ++r)
            off[nl][r] = (b0 + q * 4 + r) * (S_ * HID_)
                       + wave * 32 + nl * 16 + l;

    // 4 rotating prefetch slots: xs<u> holds x_{t+u}
    float xs0[2][4], xs1[2][4], xs2[2][4], xs3[2][4];
#pragma unroll
    for (int nl = 0; nl < 2; ++nl)
#pragma unroll
        for (int r = 0; r < 4; ++r) {
            xs0[nl][r] = xw[off[nl][r] + 0 * HID_];
            xs1[nl][r] = xw[off[nl][r] + 1 * HID_];
            xs2[nl][r] = xw[off[nl][r] + 2 * HID_];
            xs3[nl][r] = xw[off[nl][r] + 3 * HID_];
        }

    __syncthreads();   // h init visible

    // One recurrence sub-step. XS consumed (x_{t+u}), then reloaded with
    // x_{t+u+4}; the reload's wait lands 4 barriers later at next consume.
#define RNN_STEP(u, XS)                                                      \
    {                                                                        \
        bf16x8 af[4];                                                        \
        _Pragma("unroll")                                                    \
        for (int kt = 0; kt < 4; ++kt)                                       \
            af[kt] = *(const bf16x8*)                                        \
                &hl[(u) & 1][l * LDSK + kt * 32 + q * 8];                    \
        f32x4 acc0 = {0.f, 0.f, 0.f, 0.f};                                   \
        f32x4 acc1 = {0.f, 0.f, 0.f, 0.f};                                   \
        _Pragma("unroll")                                                    \
        for (int kt = 0; kt < 4; ++kt) {                                     \
            acc0 = __builtin_amdgcn_mfma_f32_16x16x32_bf16(                  \
                       af[kt], wfrag[kt][0], acc0, 0, 0, 0);                 \
            acc1 = __builtin_amdgcn_mfma_f32_16x16x32_bf16(                  \
                       af[kt], wfrag[kt][1], acc1, 0, 0, 0);                 \
        }                                                                    \
        __bf16* hdst = &hl[((u) + 1) & 1][0];                                \
        _Pragma("unroll")                                                    \
        for (int nl = 0; nl < 2; ++nl)                                       \
            _Pragma("unroll")                                                \
            for (int r = 0; r < 4; ++r) {                                    \
                const float pre = (nl ? acc1[r] : acc0[r]) + XS[nl][r];      \
                const float hf  = fast_tanh(pre);                            \
                xw[off[nl][r] + (t + (u)) * HID_] = hf;                      \
                hdst[(q * 4 + r) * LDSK + wave * 32 + nl * 16 + l] =         \
                    (__bf16)hf;                                              \
                XS[nl][r] = xw[off[nl][r] + (t + (u) + 4) * HID_];           \
            }                                                                \
        LDS_BARRIER();                                                       \
    }

#pragma unroll 1
    for (int t = 0; t < S_; t += 4) {
        RNN_STEP(0, xs0)
        RNN_STEP(1, xs1)
        RNN_STEP(2, xs2)
        RNN_STEP(3, xs3)
    }
#undef RNN_STEP
    // NOTE: final prefetches read up to 4 rows past xw (<=2 KB) -> lands in
    // the partial[] scratch region of d_ws (read-only here, values unused;
    // partial is written only later by head_kernel).
}

// ---------------------------------------------------------------------------
// K3: logits + log-softmax + per-block NLL partials   (unchanged)
// ---------------------------------------------------------------------------
__global__ __launch_bounds__(128, 2) void head_kernel(
    const float* __restrict__ hs,
    const float* __restrict__ W_out,
    const float* __restrict__ b_out,
    const int* __restrict__ labels,
    float* __restrict__ logits,
    float* __restrict__ partial)
{
    __shared__ float tile[128][129];
    __shared__ float wT[NL_][HID_];
    __shared__ float red[2];

    const int j = threadIdx.x;
    const int tpos = blockIdx.x * 128;

#pragma unroll
    for (int l = 0; l < NL_; ++l) wT[l][j] = W_out[j * NL_ + l];

    for (int p = 0; p < 128; ++p)
        tile[p][j] = hs[(size_t)(tpos + p) * HID_ + j];
    __syncthreads();

    float acc[NL_];
#pragma unroll
    for (int l = 0; l < NL_; ++l) acc[l] = b_out[l];

#pragma unroll 4
    for (int e = 0; e < HID_; ++e) {
        const float hv = tile[j][e];
#pragma unroll
        for (int l = 0; l < NL_; ++l) acc[l] += hv * wT[l][e];
    }

    float m = acc[0];
#pragma unroll
    for (int l = 1; l < NL_; ++l) m = fmaxf(m, acc[l]);
    float s = 0.f;
#pragma unroll
    for (int l = 0; l < NL_; ++l) s += __expf(acc[l] - m);
    const float logZ = m + __logf(s);

    const int lab = labels[tpos + j];
    float accl = 0.f;
#pragma unroll
    for (int l = 0; l < NL_; ++l) accl = (l == lab) ? acc[l] : accl;
    float v = logZ - accl;

#pragma unroll
    for (int off = 32; off > 0; off >>= 1) v += __shfl_down(v, off, 64);

    __syncthreads();
    if ((j & 63) == 0) red[j >> 6] = v;

    float* lt = &tile[0][0];
#pragma unroll
    for (int l = 0; l < NL_; ++l) lt[j * NL_ + l] = acc[l];
    __syncthreads();

    if (j == 0) partial[blockIdx.x] = red[0] + red[1];
    for (int i = j; i < 128 * NL_; i += 128)
        logits[(size_t)tpos * NL_ + i] = lt[i];
}

// ---------------------------------------------------------------------------
// K4: reduce partials -> loss scalar   (unchanged)
// ---------------------------------------------------------------------------
__global__ __launch_bounds__(256) void loss_kernel(
    const float* __restrict__ partial,
    float* __restrict__ out)
{
    __shared__ float red[4];
    const int j = threadIdx.x;
    float s = 0.f;
    for (int i = j; i < NBLK_HEAD; i += 256) s += partial[i];
#pragma unroll
    for (int off = 32; off > 0; off >>= 1) s += __shfl_down(s, off, 64);
    if ((j & 63) == 0) red[j >> 6] = s;
    __syncthreads();
    if (j == 0)
        out[(size_t)NPOS * NL_] =
            (red[0] + red[1] + red[2] + red[3]) * (1.0f / (float)NPOS);
}

// ---------------------------------------------------------------------------
extern "C" void kernel_launch(void* const* d_in, const int* in_sizes, int n_in,
                              void* d_out, int out_size, void* d_ws, size_t ws_size,
                              hipStream_t stream) {
    const int*   ids    = (const int*)d_in[0];
    const int*   labels = (const int*)d_in[3];
    const float* emb    = (const float*)d_in[4];
    const float* W_h    = (const float*)d_in[5];
    const float* b_h    = (const float*)d_in[6];
    const float* W_out  = (const float*)d_in[7];
    const float* b_out  = (const float*)d_in[8];
    float* out = (float*)d_out;

    float* xw      = (float*)d_ws;              // NPOS*HID floats (64 MB)
    float* partial = xw + (size_t)NPOS * HID_;  // NBLK_HEAD floats

    xw_mfma_kernel<<<NBLK_HEAD, 256, 0, stream>>>(ids, emb, W_h, b_h, xw);
    rnn_mfma_kernel<<<B_ / 16,  256, 0, stream>>>(W_h, xw);
    head_kernel   <<<NBLK_HEAD, 128, 0, stream>>>(xw, W_out, b_out, labels, out, partial);
    loss_kernel   <<<1,         256, 0, stream>>>(partial, out);
}

// Round 6
// 638.667 us; speedup vs baseline: 1.9181x; 1.0096x over previous
//
#include <hip/hip_runtime.h>
#include <hip/hip_bf16.h>
#include <math.h>

#define B_   128
#define S_   1024
#define EMB_ 128
#define HID_ 128
#define NL_  9
#define NPOS (B_ * S_)          // 131072
#define NBLK (NPOS / 128)       // 1024

typedef __bf16 bf16x4 __attribute__((ext_vector_type(4)));
typedef __bf16 bf16x8 __attribute__((ext_vector_type(8)));
typedef float  f32x4  __attribute__((ext_vector_type(4)));

#define LDSK 136   // 128 + 8 bf16 pad for h tiles (272B row stride)

// LDS-only barrier: skip the vmcnt(0) drain __syncthreads() would add.
#define LDS_BARRIER() __asm__ volatile("s_waitcnt lgkmcnt(0)\n\ts_barrier" ::: "memory")

__device__ __forceinline__ float fast_tanh(float x) {
    float e = __builtin_amdgcn_exp2f(x * 2.885390081777927f);  // v_exp_f32
    return 1.0f - 2.0f * __builtin_amdgcn_rcpf(e + 1.0f);
}

// ---------------------------------------------------------------------------
// K1: xq = bf16( gather(emb, ids) @ Wx + b_h ), written in the rnn kernel's
// staged-lane layout: elem index = cb*S*2048 + t*2048 + tid*8 + idx, where
// for batch b: cb=b>>4, qd=(b>>2)&3, rd=b&3; tid = wave*64 + qd*16 + l
// (wave = col>>5, l = col&15); idx = ((col>>4)&1)*4 + rd.
// ---------------------------------------------------------------------------
__global__ __launch_bounds__(256, 2) void xw_mfma_kernel(
    const int* __restrict__ ids,
    const float* __restrict__ emb,
    const float* __restrict__ W_h,
    const float* __restrict__ b_h,
    __bf16* __restrict__ xq)
{
    const int tid  = threadIdx.x;
    const int wave = tid >> 6;
    const int lane = tid & 63;
    const int l    = lane & 15;
    const int q    = lane >> 4;
    const int base = blockIdx.x * 128;

    const int bglob = blockIdx.x >> 3;          // batch (S_=1024 = 8*128)
    const int T0    = (blockIdx.x & 7) * 128;   // s offset within batch
    const int cb    = bglob >> 4;
    const int qd    = (bglob >> 2) & 3;
    const int rd    = bglob & 3;
    __bf16* xqb = xq + (size_t)cb * S_ * 2048;

    __shared__ int ids_s[128];
    __shared__ __align__(16) __bf16 A[128][LDSK];

    if (tid < 128) ids_s[tid] = ids[base + tid];

    // B fragments (Wx): n = wave*32 + nl*16 + l, k = kt*32 + q*8 + j
    bf16x8 wfrag[4][2];
#pragma unroll
    for (int kt = 0; kt < 4; ++kt)
#pragma unroll
        for (int nl = 0; nl < 2; ++nl) {
            const int n = wave * 32 + nl * 16 + l;
            const int kb = kt * 32 + q * 8;
            bf16x8 f;
#pragma unroll
            for (int j = 0; j < 8; ++j)
                f[j] = (__bf16)W_h[(size_t)(kb + j) * HID_ + n];
            wfrag[kt][nl] = f;
        }
    float bhv[2];
#pragma unroll
    for (int nl = 0; nl < 2; ++nl)
        bhv[nl] = b_h[wave * 32 + nl * 16 + l];

    __syncthreads();   // ids_s ready

    const int lr = tid >> 5;          // 0..7
    const int c4 = (tid & 31) * 4;    // 0..124
#pragma unroll 4
    for (int r0 = 0; r0 < 128; r0 += 8) {
        const int row = r0 + lr;
        const float4 v = *(const float4*)&emb[(size_t)ids_s[row] * EMB_ + c4];
        bf16x4 b = {(__bf16)v.x, (__bf16)v.y, (__bf16)v.z, (__bf16)v.w};
        *(bf16x4*)&A[row][c4] = b;
    }
    __syncthreads();   // A ready

#pragma unroll 1
    for (int mt = 0; mt < 8; ++mt) {
        bf16x8 afrag[4];
#pragma unroll
        for (int kt = 0; kt < 4; ++kt)
            afrag[kt] = *(const bf16x8*)&A[mt * 16 + l][kt * 32 + q * 8];

        f32x4 acc0 = {0.f, 0.f, 0.f, 0.f};
        f32x4 acc1 = {0.f, 0.f, 0.f, 0.f};
#pragma unroll
        for (int kt = 0; kt < 4; ++kt) {
            acc0 = __builtin_amdgcn_mfma_f32_16x16x32_bf16(
                       afrag[kt], wfrag[kt][0], acc0, 0, 0, 0);
            acc1 = __builtin_amdgcn_mfma_f32_16x16x32_bf16(
                       afrag[kt], wfrag[kt][1], acc1, 0, 0, 0);
        }
        // scatter in staged-lane layout
#pragma unroll
        for (int nl = 0; nl < 2; ++nl) {
            const int tidd = wave * 64 + qd * 16 + l;
            const int idx  = nl * 4 + rd;
#pragma unroll
            for (int r = 0; r < 4; ++r) {
                const int t = T0 + mt * 16 + q * 4 + r;
                const float vv = (nl ? acc1[r] : acc0[r]) + bhv[nl];
                xqb[(size_t)t * 2048 + tidd * 8 + idx] = (__bf16)vv;
            }
        }
    }
}

// ---------------------------------------------------------------------------
// K2 (R6): fused recurrence + head GEMM. 8 blocks x 256 thr, 16 batches/blk.
// x staged into LDS in 16-step chunks via global_load_lds (double-buffered,
// prefetched 1 chunk ahead). Per step: 1 ds_read_b128 (x) + 4 ds_read_b128
// (h) + 8 MFMA (h@Wh) [+4 MFMA h@W_out on wave 0] + tanh + 8 ds_write_b16.
// Logits written directly to d_out (one step delayed: af holds h_{t-1}'s
// output state). No hs materialization.
// ---------------------------------------------------------------------------
#define CHUNK 16

__global__ __launch_bounds__(256, 1) void rnn_fused_kernel(
    const float* __restrict__ W_h,
    const __bf16* __restrict__ xq,
    const float* __restrict__ W_out,
    const float* __restrict__ b_out,
    float* __restrict__ logits)   // d_out, [b][s][NL_]
{
    const int tid  = threadIdx.x;
    const int wave = tid >> 6;
    const int lane = tid & 63;
    const int l    = lane & 15;
    const int q    = lane >> 4;
    const int cb   = blockIdx.x;

    // Wh fragments
    bf16x8 wfrag[4][2];
#pragma unroll
    for (int kt = 0; kt < 4; ++kt)
#pragma unroll
        for (int nl = 0; nl < 2; ++nl) {
            const int n = wave * 32 + nl * 16 + l;
            const int kb = kt * 32 + q * 8;
            bf16x8 f;
#pragma unroll
            for (int j = 0; j < 8; ++j)
                f[j] = (__bf16)W_h[(size_t)(EMB_ + kb + j) * HID_ + n];
            wfrag[kt][nl] = f;
        }
    // W_out fragments (16-col tile, cols >= NL_ zeroed)
    bf16x8 wof[4];
#pragma unroll
    for (int kt = 0; kt < 4; ++kt) {
        bf16x8 f;
#pragma unroll
        for (int j = 0; j < 8; ++j)
            f[j] = (l < NL_) ? (__bf16)W_out[(size_t)(kt * 32 + q * 8 + j) * NL_ + l]
                             : (__bf16)0.f;
        wof[kt] = f;
    }
    const float bo = (l < NL_) ? b_out[l] : 0.f;

    __shared__ __align__(16) __bf16 hl[2][16 * LDSK];
    __shared__ __align__(16) __bf16 xstage[2][CHUNK * 256 * 8];   // 2 x 64 KB

    for (int i = tid; i < 2 * 16 * LDSK; i += 256)
        (&hl[0][0])[i] = (__bf16)0.f;

    const __bf16* gsrc = xq + (size_t)cb * S_ * 2048;

    // stage chunk T into buffer bf: identity byte mapping, 16 x 1KB per wave
#define STAGE(bf, T)                                                          \
    {                                                                         \
        _Pragma("unroll")                                                     \
        for (int i = 0; i < 16; ++i)                                          \
            __builtin_amdgcn_global_load_lds(                                 \
                (const __attribute__((address_space(1))) unsigned int*)       \
                    (gsrc + (size_t)(T) * 2048 + wave * 8192 + i * 512 +      \
                     lane * 8),                                               \
                (__attribute__((address_space(3))) unsigned int*)             \
                    &xstage[bf][wave * 8192 + i * 512],                       \
                16, 0, 0);                                                    \
    }

    STAGE(0, 0)
    __syncthreads();   // drains vmcnt + lgkm: chunk 0 + h init visible

    // logit store pointers: row r -> batch cb*16 + q*4 + r, col l
    float* lp[4];
#pragma unroll
    for (int r = 0; r < 4; ++r)
        lp[r] = logits + ((size_t)(cb * 16 + q * 4 + r) * S_) * NL_ + l;

    int buf = 0;
#pragma unroll 1
    for (int T = 0; T < S_; T += CHUNK) {
        if (T + CHUNK < S_) STAGE(buf ^ 1, T + CHUNK)
#pragma unroll 2
        for (int tt = 0; tt < CHUNK; ++tt) {
            const int t = T + tt;

            // x for this step: one conflict-free b128 per lane
            const bf16x8 xv =
                *(const bf16x8*)&xstage[buf][(tt * 256 + tid) * 8];

            // A fragments = state entering step t (= hs[t-1])
            bf16x8 af[4];
#pragma unroll
            for (int kt = 0; kt < 4; ++kt)
                af[kt] = *(const bf16x8*)
                    &hl[tt & 1][l * LDSK + kt * 32 + q * 8];

            // head GEMM for step t-1 (wave 0 only), from af
            if (wave == 0) {
                f32x4 lacc = {0.f, 0.f, 0.f, 0.f};
#pragma unroll
                for (int kt = 0; kt < 4; ++kt)
                    lacc = __builtin_amdgcn_mfma_f32_16x16x32_bf16(
                               af[kt], wof[kt], lacc, 0, 0, 0);
                if (t > 0 && l < NL_) {
#pragma unroll
                    for (int r = 0; r < 4; ++r)
                        lp[r][(size_t)(t - 1) * NL_] = lacc[r] + bo;
                }
            }

            // recurrence GEMM
            f32x4 acc0 = {0.f, 0.f, 0.f, 0.f};
            f32x4 acc1 = {0.f, 0.f, 0.f, 0.f};
#pragma unroll
            for (int kt = 0; kt < 4; ++kt) {
                acc0 = __builtin_amdgcn_mfma_f32_16x16x32_bf16(
                           af[kt], wfrag[kt][0], acc0, 0, 0, 0);
                acc1 = __builtin_amdgcn_mfma_f32_16x16x32_bf16(
                           af[kt], wfrag[kt][1], acc1, 0, 0, 0);
            }

            // epilogue: +x, tanh, stage h_{t+1}
            __bf16* hdst = &hl[(tt + 1) & 1][0];
#pragma unroll
            for (int nl = 0; nl < 2; ++nl)
#pragma unroll
                for (int r = 0; r < 4; ++r) {
                    const float pre = (nl ? acc1[r] : acc0[r])
                                    + (float)xv[nl * 4 + r];
                    const float hf  = fast_tanh(pre);
                    hdst[(q * 4 + r) * LDSK + wave * 32 + nl * 16 + l] =
                        (__bf16)hf;
                }
            LDS_BARRIER();
        }
        __syncthreads();   // next chunk's DMA landed & visible; swap buffers
        buf ^= 1;
    }

    // final logits for t = S_-1 from the last state (in hl[0]: S_ even)
    if (wave == 0) {
        bf16x8 af[4];
#pragma unroll
        for (int kt = 0; kt < 4; ++kt)
            af[kt] = *(const bf16x8*)&hl[0][l * LDSK + kt * 32 + q * 8];
        f32x4 lacc = {0.f, 0.f, 0.f, 0.f};
#pragma unroll
        for (int kt = 0; kt < 4; ++kt)
            lacc = __builtin_amdgcn_mfma_f32_16x16x32_bf16(
                       af[kt], wof[kt], lacc, 0, 0, 0);
        if (l < NL_) {
#pragma unroll
            for (int r = 0; r < 4; ++r)
                lp[r][(size_t)(S_ - 1) * NL_] = lacc[r] + bo;
        }
    }
#undef STAGE
}

// ---------------------------------------------------------------------------
// K3: softmax + NLL partials straight from the logits in d_out.
// ---------------------------------------------------------------------------
__global__ __launch_bounds__(128, 2) void nll_kernel(
    const float* __restrict__ logits,
    const int* __restrict__ labels,
    float* __restrict__ partial)
{
    __shared__ float red[2];
    const int j = threadIdx.x;
    const int p = blockIdx.x * 128 + j;

    float lg[NL_];
    const float* src = logits + (size_t)p * NL_;
#pragma unroll
    for (int i = 0; i < NL_; ++i) lg[i] = src[i];

    float m = lg[0];
#pragma unroll
    for (int i = 1; i < NL_; ++i) m = fmaxf(m, lg[i]);
    float s = 0.f;
#pragma unroll
    for (int i = 0; i < NL_; ++i) s += __expf(lg[i] - m);
    const float logZ = m + __logf(s);

    const int lab = labels[p];
    float accl = 0.f;
#pragma unroll
    for (int i = 0; i < NL_; ++i) accl = (i == lab) ? lg[i] : accl;
    float v = logZ - accl;

#pragma unroll
    for (int off = 32; off > 0; off >>= 1) v += __shfl_down(v, off, 64);
    if ((j & 63) == 0) red[j >> 6] = v;
    __syncthreads();
    if (j == 0) partial[blockIdx.x] = red[0] + red[1];
}

// ---------------------------------------------------------------------------
// K4: reduce partials -> loss scalar
// ---------------------------------------------------------------------------
__global__ __launch_bounds__(256) void loss_kernel(
    const float* __restrict__ partial,
    float* __restrict__ out)
{
    __shared__ float red[4];
    const int j = threadIdx.x;
    float s = 0.f;
    for (int i = j; i < NBLK; i += 256) s += partial[i];
#pragma unroll
    for (int off = 32; off > 0; off >>= 1) s += __shfl_down(s, off, 64);
    if ((j & 63) == 0) red[j >> 6] = s;
    __syncthreads();
    if (j == 0)
        out[(size_t)NPOS * NL_] =
            (red[0] + red[1] + red[2] + red[3]) * (1.0f / (float)NPOS);
}

// ---------------------------------------------------------------------------
extern "C" void kernel_launch(void* const* d_in, const int* in_sizes, int n_in,
                              void* d_out, int out_size, void* d_ws, size_t ws_size,
                              hipStream_t stream) {
    const int*   ids    = (const int*)d_in[0];
    const int*   labels = (const int*)d_in[3];
    const float* emb    = (const float*)d_in[4];
    const float* W_h    = (const float*)d_in[5];
    const float* b_h    = (const float*)d_in[6];
    const float* W_out  = (const float*)d_in[7];
    const float* b_out  = (const float*)d_in[8];
    float* out = (float*)d_out;

    __bf16* xq     = (__bf16*)d_ws;                              // 32 MB
    float*  partial = (float*)((char*)d_ws + (size_t)NPOS * HID_ * sizeof(__bf16));

    xw_mfma_kernel <<<NBLK,    256, 0, stream>>>(ids, emb, W_h, b_h, xq);
    rnn_fused_kernel<<<B_ / 16, 256, 0, stream>>>(W_h, xq, W_out, b_out, out);
    nll_kernel     <<<NBLK,    128, 0, stream>>>(out, labels, partial);
    loss_kernel    <<<1,       256, 0, stream>>>(partial, out);
}